// Round 1
// 1427.466 us; speedup vs baseline: 1.1137x; 1.1137x over previous
//
#include <hip/hip_runtime.h>
#include <hip/hip_bf16.h>
#include <math.h>

// Problem constants
#define BB   4
#define SS   1024
#define VV   256
#define KDIM 64
#define HH   8
#define TT   4
#define EPSV 1e-3f
#define SCL  0.125f        // KD^-0.5
#define INV2048 4.8828125e-4f

typedef float f4 __attribute__((ext_vector_type(4)));
typedef short bf8 __attribute__((ext_vector_type(8)));       // 8 bf16
typedef _Float16 h8 __attribute__((ext_vector_type(8)));     // 8 f16
typedef _Float16 h4 __attribute__((ext_vector_type(4)));

#define LDP 68   // fp32 GEMM LDS stride (floats)
#define LKP 72   // attention 16-bit LDS stride (shorts/halves; 36 dwords -> 2-way, free)
#define LHS 68   // split-f16 GEMM LDS stride (halves; 34 dwords -> 2-way, free)

__device__ __forceinline__ short f2bf(float x) {
  __hip_bfloat16 h = __float2bfloat16(x);   // RNE
  return *reinterpret_cast<short*>(&h);
}
__device__ __forceinline__ float bf2f(short h) {
  union { unsigned u; float f; } cv;
  cv.u = ((unsigned)(unsigned short)h) << 16;
  return cv.f;
}

// ---------------------------------------------------------------------------
// fp32 GEMM core (R4, proven) — used only by k_in_dense (1 dispatch).
// ---------------------------------------------------------------------------
__device__ __forceinline__ void gemm_core(
    const float* __restrict__ A, const float* __restrict__ Bm, int ldb,
    float acc[4][4], float (*As)[LDP], float (*Bs)[LDP])
{
  const int tid = threadIdx.x;
  const int tx = tid & 15, ty = tid >> 4;
#pragma unroll
  for (int i = 0; i < 4; i++)
#pragma unroll
    for (int j = 0; j < 4; j++) acc[i][j] = 0.f;

  for (int k0 = 0; k0 < 256; k0 += 16) {
#pragma unroll
    for (int l = 0; l < 4; l++) {
      int e = tid + l * 256;
      int r = e >> 4, kk = e & 15;
      As[kk][r] = A[r * 256 + k0 + kk];
      int rb = e >> 6, nn = e & 63;
      Bs[rb][nn] = Bm[(k0 + rb) * ldb + nn];
    }
    __syncthreads();
#pragma unroll
    for (int kk = 0; kk < 16; kk++) {
      f4 av = *(const f4*)&As[kk][ty * 4];
      f4 bv = *(const f4*)&Bs[kk][tx * 4];
#pragma unroll
      for (int i = 0; i < 4; i++)
#pragma unroll
        for (int j = 0; j < 4; j++)
          acc[i][j] += av[i] * bv[j];
    }
    __syncthreads();
  }
}

// ---------------------------------------------------------------------------
// net0 = x @ W_in, broadcast into all H head slots (R4 verbatim)
// ---------------------------------------------------------------------------
__global__ __launch_bounds__(256) void k_in_dense(
    const float* __restrict__ x, const float* __restrict__ Win,
    float* __restrict__ net)
{
  __shared__ __align__(16) float As[16][LDP];
  __shared__ __align__(16) float Bs[16][LDP];
  const int mt = blockIdx.x, nt = blockIdx.y;
  float acc[4][4];
  gemm_core(x + mt * 64 * 256, Win + nt * 64, 256, acc, As, Bs);
  const int tx = threadIdx.x & 15, ty = threadIdx.x >> 4;
#pragma unroll
  for (int i = 0; i < 4; i++) {
    f4 v;
#pragma unroll
    for (int j = 0; j < 4; j++) v[j] = acc[i][j];
    int row = mt * 64 + ty * 4 + i;
    int col = nt * 64 + tx * 4;
    for (int h = 0; h < HH; h++)
      *(f4*)&net[(size_t)h * 1048576 + row * 256 + col] = v;
  }
}

// ---------------------------------------------------------------------------
// Weight prep (per t): transpose + split into f16 hi/lo, layout [n][k(256)].
// Regions in halves: q: h*16384 ; k: 131072+h*16384 ; v: 262144+h*65536 ;
// d: 786432+h*65536. grid (10, 4 kb, 8 h): x 0=q,1=k,2..5=v,6..9=d.
// ---------------------------------------------------------------------------
__global__ __launch_bounds__(256) void k_prep(
    const float* __restrict__ Wq, const float* __restrict__ Wk,
    const float* __restrict__ Wv, const float* __restrict__ Wd,
    _Float16* __restrict__ oh, _Float16* __restrict__ ol, int t)
{
  __shared__ __align__(16) _Float16 Th[64][LHS];
  __shared__ __align__(16) _Float16 Tl[64][LHS];
  const int xb = blockIdx.x, kb = blockIdx.y, h = blockIdx.z;
  const int tid = threadIdx.x;
  const float* src; int N, nb; size_t dbase;
  if (xb == 0)      { src = Wq; N = 64;  nb = 0;      dbase = (size_t)h * 16384; }
  else if (xb == 1) { src = Wk; N = 64;  nb = 0;      dbase = 131072 + (size_t)h * 16384; }
  else if (xb < 6)  { src = Wv; N = 256; nb = xb - 2; dbase = 262144 + (size_t)h * 65536; }
  else              { src = Wd; N = 256; nb = xb - 6; dbase = 786432 + (size_t)h * 65536; }
  src += (size_t)(h * TT + t) * 256 * N;
  // load 64(k) x 64(n) tile coalesced, split to hi/lo in LDS
#pragma unroll
  for (int i = 0; i < 4; i++) {
    int fi = tid + i * 256;
    int r = fi >> 4, c4 = fi & 15;
    f4 w = *(const f4*)&src[(size_t)(kb * 64 + r) * N + nb * 64 + c4 * 4];
    h4 hv, lv;
#pragma unroll
    for (int j = 0; j < 4; j++) {
      _Float16 hi = (_Float16)w[j];
      hv[j] = hi;
      lv[j] = (_Float16)((w[j] - (float)hi) * 2048.f);
    }
    *(h4*)&Th[r][c4 * 4] = hv;
    *(h4*)&Tl[r][c4 * 4] = lv;
  }
  __syncthreads();
  // write transposed [n][k], coalesced along k
#pragma unroll
  for (int i = 0; i < 4; i++) {
    int fo = tid + i * 256;
    int nr = fo >> 4, k4 = fo & 15;
    h4 hv, lv;
#pragma unroll
    for (int j = 0; j < 4; j++) { hv[j] = Th[k4 * 4 + j][nr]; lv[j] = Tl[k4 * 4 + j][nr]; }
    size_t d = dbase + (size_t)(nb * 64 + nr) * 256 + kb * 64 + k4 * 4;
    *(h4*)&oh[d] = hv;
    *(h4*)&ol[d] = lv;
  }
}

// ---------------------------------------------------------------------------
// Split-f16 MFMA GEMM core: 64x64 tile, K=256 (4 chunks of 64).
// C = A@B with A fp32 (split on the fly), B prepped hi/lo [n][256].
// acc = main + corr/2048 (dropped lo*lo ~ 2^-22). Block 256 = 4 waves,
// wave wv owns n-cols [wv*16,wv*16+16). cm[mf]: rows mf*16+quad*4+r, col ln.
// ---------------------------------------------------------------------------
__device__ __forceinline__ void mm_core(
    const float* __restrict__ A,          // tile row 0, lda=256
    const _Float16* __restrict__ Bh,      // n-tile base
    const _Float16* __restrict__ Bl,
    f4 cm[4],
    _Float16 (*Ah)[LHS], _Float16 (*Al)[LHS])
{
  const int tid = threadIdx.x, wv = tid >> 6, lane = tid & 63;
  const int ln = lane & 15, quad = lane >> 4;
  f4 mn[4], cr[4];
#pragma unroll
  for (int mf = 0; mf < 4; mf++) {
    mn[mf] = (f4){0.f, 0.f, 0.f, 0.f};
    cr[mf] = (f4){0.f, 0.f, 0.f, 0.f};
  }
  const _Float16* bhp = Bh + (size_t)(wv * 16 + ln) * 256;
  const _Float16* blp = Bl + (size_t)(wv * 16 + ln) * 256;

  for (int kc = 0; kc < 4; kc++) {
    // stage A chunk 64x64: coalesced f4 loads, split, LDS h4 stores
#pragma unroll
    for (int i = 0; i < 4; i++) {
      int fi = tid + i * 256;
      int r = fi >> 4, c4 = fi & 15;
      f4 w = *(const f4*)&A[(size_t)r * 256 + kc * 64 + c4 * 4];
      h4 hv, lv;
#pragma unroll
      for (int j = 0; j < 4; j++) {
        _Float16 hi = (_Float16)w[j];
        hv[j] = hi;
        lv[j] = (_Float16)((w[j] - (float)hi) * 2048.f);
      }
      *(h4*)&Ah[r][c4 * 4] = hv;
      *(h4*)&Al[r][c4 * 4] = lv;
    }
    // B fragments straight from global (prepped, L2-hot)
    h8 bh0 = *(const h8*)&bhp[kc * 64 + quad * 8];
    h8 bh1 = *(const h8*)&bhp[kc * 64 + 32 + quad * 8];
    h8 bl0 = *(const h8*)&blp[kc * 64 + quad * 8];
    h8 bl1 = *(const h8*)&blp[kc * 64 + 32 + quad * 8];
    __syncthreads();
#pragma unroll
    for (int mf = 0; mf < 4; mf++) {
      h8 ah0 = *(const h8*)&Ah[mf * 16 + ln][quad * 8];
      h8 ah1 = *(const h8*)&Ah[mf * 16 + ln][32 + quad * 8];
      h8 al0 = *(const h8*)&Al[mf * 16 + ln][quad * 8];
      h8 al1 = *(const h8*)&Al[mf * 16 + ln][32 + quad * 8];
      mn[mf] = __builtin_amdgcn_mfma_f32_16x16x32_f16(ah0, bh0, mn[mf], 0, 0, 0);
      mn[mf] = __builtin_amdgcn_mfma_f32_16x16x32_f16(ah1, bh1, mn[mf], 0, 0, 0);
      cr[mf] = __builtin_amdgcn_mfma_f32_16x16x32_f16(ah0, bl0, cr[mf], 0, 0, 0);
      cr[mf] = __builtin_amdgcn_mfma_f32_16x16x32_f16(ah1, bl1, cr[mf], 0, 0, 0);
      cr[mf] = __builtin_amdgcn_mfma_f32_16x16x32_f16(al0, bh0, cr[mf], 0, 0, 0);
      cr[mf] = __builtin_amdgcn_mfma_f32_16x16x32_f16(al1, bh1, cr[mf], 0, 0, 0);
    }
    __syncthreads();
  }
#pragma unroll
  for (int mf = 0; mf < 4; mf++)
#pragma unroll
    for (int r = 0; r < 4; r++)
      cm[mf][r] = mn[mf][r] + cr[mf][r] * INV2048;
}

// ---------------------------------------------------------------------------
// QKV GEMM: q/k -> split-f16 hi/lo in natural [s][kd] layout (MFMA fragment
// layout for the attention kernel); v -> bf16 hi/lo transposed [h*4+b][vcol][s].
// grid (64 mt, 6 nt [0:q 1:k 2..5:v], 8 h)
// ---------------------------------------------------------------------------
__global__ __launch_bounds__(256) void k_mm_qkv(
    const float* __restrict__ net,
    const _Float16* __restrict__ wph, const _Float16* __restrict__ wpl,
    _Float16* __restrict__ qph, _Float16* __restrict__ qpl,
    _Float16* __restrict__ kph, _Float16* __restrict__ kpl,
    short* __restrict__ vth, short* __restrict__ vtl)
{
  __shared__ __align__(16) _Float16 Ah[64][LHS];
  __shared__ __align__(16) _Float16 Al[64][LHS];
  const int mt = blockIdx.x, nt = blockIdx.y, h = blockIdx.z;
  const int tid = threadIdx.x, wv = tid >> 6, lane = tid & 63;
  const int ln = lane & 15, quad = lane >> 4;
  const float* A = net + (size_t)h * 1048576 + (size_t)mt * 64 * 256;
  size_t bbase;
  if (nt == 0)      bbase = (size_t)h * 16384;
  else if (nt == 1) bbase = 131072 + (size_t)h * 16384;
  else              bbase = 262144 + (size_t)h * 65536 + (size_t)(nt - 2) * 64 * 256;
  f4 cm[4];
  mm_core(A, wph + bbase, wpl + bbase, cm, Ah, Al);

  if (nt <= 1) {
    _Float16* dh = (nt == 0) ? qph : kph;
    _Float16* dl = (nt == 0) ? qpl : kpl;
    int col = wv * 16 + ln;
#pragma unroll
    for (int mf = 0; mf < 4; mf++)
#pragma unroll
      for (int r = 0; r < 4; r++) {
        int row = mt * 64 + mf * 16 + quad * 4 + r;
        int b_ = row >> 10, sI = row & 1023;
        float v = cm[mf][r];
        _Float16 hi = (_Float16)v;
        size_t idx = ((size_t)(h * 4 + b_) * 1024 + sI) * 64 + col;
        dh[idx] = hi;
        dl[idx] = (_Float16)((v - (float)hi) * 2048.f);
      }
  } else {
    int c = (nt - 2) * 64 + wv * 16 + ln;
#pragma unroll
    for (int mf = 0; mf < 4; mf++)
#pragma unroll
      for (int r = 0; r < 4; r++) {
        int row = mt * 64 + mf * 16 + quad * 4 + r;
        int b_ = row >> 10, sI = row & 1023;
        float v = cm[mf][r];
        short hi = f2bf(v);
        size_t idx = ((size_t)(h * 4 + b_) * 256 + c) * 1024 + sI;
        vth[idx] = hi;
        vtl[idx] = f2bf(v - bf2f(hi));
      }
  }
}

// ---------------------------------------------------------------------------
// Dense GEMM: tmp = net + relu(net @ Wd). grid (64 mt, 4 nt, 8 h)
// ---------------------------------------------------------------------------
__global__ __launch_bounds__(256) void k_mm_dense(
    const float* __restrict__ net,
    const _Float16* __restrict__ wph, const _Float16* __restrict__ wpl,
    float* __restrict__ tmp)
{
  __shared__ __align__(16) _Float16 Ah[64][LHS];
  __shared__ __align__(16) _Float16 Al[64][LHS];
  const int mt = blockIdx.x, nt = blockIdx.y, h = blockIdx.z;
  const int tid = threadIdx.x, wv = tid >> 6, lane = tid & 63;
  const int ln = lane & 15, quad = lane >> 4;
  const float* A = net + (size_t)h * 1048576 + (size_t)mt * 64 * 256;
  size_t bbase = 786432 + (size_t)h * 65536 + (size_t)nt * 64 * 256;
  f4 cm[4];
  mm_core(A, wph + bbase, wpl + bbase, cm, Ah, Al);

  int col = nt * 64 + wv * 16 + ln;
#pragma unroll
  for (int mf = 0; mf < 4; mf++)
#pragma unroll
    for (int r = 0; r < 4; r++) {
      int row = mt * 64 + mf * 16 + quad * 4 + r;
      size_t idx = (size_t)h * 1048576 + (size_t)row * 256 + col;
      tmp[idx] = net[idx] + fmaxf(cm[mf][r], 0.f);
    }
}

// ---------------------------------------------------------------------------
// Flash attention — MFMA everywhere.
// QK^T: split-f16 MFMA (Q frags in registers, K staged hi/lo in LDS).
// softmax on MFMA C-layout (rows wv*16+quad*4+r == old ty*4+r mapping).
// PV: split-bf16 MFMA (verbatim from previous version).
// grid (16 q-tiles, 4 batch, 8 heads)
// ---------------------------------------------------------------------------
__global__ __launch_bounds__(256, 2) void k_attn(
    const _Float16* __restrict__ qfh, const _Float16* __restrict__ qfl,
    const _Float16* __restrict__ kfh, const _Float16* __restrict__ kfl,
    const short* __restrict__ vth, const short* __restrict__ vtl,
    float* __restrict__ ob)
{
  __shared__ __align__(16) char smem[55296];
  _Float16 (*Kh)[LKP] = (_Float16(*)[LKP])(smem);            // 9,216 B
  _Float16 (*Kl)[LKP] = (_Float16(*)[LKP])(smem + 9216);     // 9,216 B
  short (*Vh)[LKP]  = (short(*)[LKP])(smem + 18432);         // 9,216 B
  short (*Vl2)[LKP] = (short(*)[LKP])(smem + 27648);         // 9,216 B
  short (*Ph)[LKP]  = (short(*)[LKP])(smem + 36864);         // 9,216 B
  short (*Pl)[LKP]  = (short(*)[LKP])(smem + 46080);         // 9,216 B

  const int qt = blockIdx.x, b = blockIdx.y, h = blockIdx.z;
  const int tid = threadIdx.x;
  const int wv = tid >> 6, lane = tid & 63, ln = lane & 15, quad = lane >> 4;
  const int hb = h * 4 + b;

  // Q fragments: wave wv owns q-rows [qt*64+wv*16, +16). A-frag: lane ln = row,
  // k = quad*8 (+32 for second chunk). Loaded once, kept in registers.
  const _Float16* qgh = qfh + ((size_t)hb * 1024 + qt * 64 + wv * 16 + ln) * 64;
  const _Float16* qgl = qfl + ((size_t)hb * 1024 + qt * 64 + wv * 16 + ln) * 64;
  h8 aqh0 = *(const h8*)&qgh[quad * 8];
  h8 aqh1 = *(const h8*)&qgh[32 + quad * 8];
  h8 aql0 = *(const h8*)&qgl[quad * 8];
  h8 aql1 = *(const h8*)&qgl[32 + quad * 8];

  const _Float16* kgh = kfh + (size_t)hb * 65536;   // [1024 s][64 kd]
  const _Float16* kgl = kfl + (size_t)hb * 65536;
  const short* vhg = vth + (size_t)hb * 262144;     // [256 vcol][1024 s]
  const short* vlg = vtl + (size_t)hb * 262144;

  float m[4] = {-1e30f, -1e30f, -1e30f, -1e30f};
  float l[4] = {0.f, 0.f, 0.f, 0.f};
  f4 O[16];
#pragma unroll
  for (int nt = 0; nt < 16; nt++) O[nt] = (f4){0.f, 0.f, 0.f, 0.f};

  for (int kt = 0; kt < 16; kt++) {
    // stage K tile (64 keys x 64 kd, hi/lo) — coalesced 16B loads/stores
#pragma unroll
    for (int i = 0; i < 2; i++) {
      int e = tid + i * 256;
      int r = e >> 3, c8 = e & 7;
      *(h8*)&Kh[r][c8 * 8] = *(const h8*)&kgh[(size_t)(kt * 64 + r) * 64 + c8 * 8];
      *(h8*)&Kl[r][c8 * 8] = *(const h8*)&kgl[(size_t)(kt * 64 + r) * 64 + c8 * 8];
    }
    __syncthreads();   // B1

    // QK^T: per wave, 1 m-frag (its 16 q-rows) x 4 n-frags (64 keys), K=64.
    // sv[nf][r] = S[row=quad*4+r][key=nf*16+ln] * SCL
    f4 sv[4];
#pragma unroll
    for (int nf = 0; nf < 4; nf++) {
      h8 bkh0 = *(const h8*)&Kh[nf * 16 + ln][quad * 8];
      h8 bkh1 = *(const h8*)&Kh[nf * 16 + ln][32 + quad * 8];
      h8 bkl0 = *(const h8*)&Kl[nf * 16 + ln][quad * 8];
      h8 bkl1 = *(const h8*)&Kl[nf * 16 + ln][32 + quad * 8];
      f4 mn = (f4){0.f, 0.f, 0.f, 0.f};
      f4 cr = (f4){0.f, 0.f, 0.f, 0.f};
      mn = __builtin_amdgcn_mfma_f32_16x16x32_f16(aqh0, bkh0, mn, 0, 0, 0);
      mn = __builtin_amdgcn_mfma_f32_16x16x32_f16(aqh1, bkh1, mn, 0, 0, 0);
      cr = __builtin_amdgcn_mfma_f32_16x16x32_f16(aqh0, bkl0, cr, 0, 0, 0);
      cr = __builtin_amdgcn_mfma_f32_16x16x32_f16(aqh1, bkl1, cr, 0, 0, 0);
      cr = __builtin_amdgcn_mfma_f32_16x16x32_f16(aql0, bkh0, cr, 0, 0, 0);
      cr = __builtin_amdgcn_mfma_f32_16x16x32_f16(aql1, bkh1, cr, 0, 0, 0);
#pragma unroll
      for (int r = 0; r < 4; r++) sv[nf][r] = (mn[r] + cr[r] * INV2048) * SCL;
    }

    // online softmax: row = quad*4+r; 64 keys = 4 nf (local) x 16 ln (shfl).
    float alpha[4];
#pragma unroll
    for (int r = 0; r < 4; r++) {
      float mloc = fmaxf(fmaxf(sv[0][r], sv[1][r]), fmaxf(sv[2][r], sv[3][r]));
#pragma unroll
      for (int d = 1; d < 16; d <<= 1)
        mloc = fmaxf(mloc, __shfl_xor(mloc, d, 64));
      float mnew = fmaxf(m[r], mloc);
      alpha[r] = __expf(m[r] - mnew);
      float ls = 0.f;
#pragma unroll
      for (int nf = 0; nf < 4; nf++) {
        float p = __expf(sv[nf][r] - mnew);
        sv[nf][r] = p;
        ls += p;
      }
#pragma unroll
      for (int d = 1; d < 16; d <<= 1) ls += __shfl_xor(ls, d, 64);
      l[r] = l[r] * alpha[r] + ls;
      m[r] = mnew;
    }
#pragma unroll
    for (int nt = 0; nt < 16; nt++)
#pragma unroll
      for (int i = 0; i < 4; i++) O[nt][i] *= alpha[i];

    // P -> split bf16 hi/lo in LDS (each wave writes its own 16 rows)
#pragma unroll
    for (int nf = 0; nf < 4; nf++)
#pragma unroll
      for (int r = 0; r < 4; r++) {
        float p = sv[nf][r];
        short hi = f2bf(p);
        Ph[wv * 16 + quad * 4 + r][nf * 16 + ln] = hi;
        Pl[wv * 16 + quad * 4 + r][nf * 16 + ln] = f2bf(p - bf2f(hi));
      }
    __syncthreads();   // B2

    bf8 ph0 = *(const bf8*)&Ph[wv * 16 + ln][quad * 8];
    bf8 ph1 = *(const bf8*)&Ph[wv * 16 + ln][32 + quad * 8];
    bf8 pl0 = *(const bf8*)&Pl[wv * 16 + ln][quad * 8];
    bf8 pl1 = *(const bf8*)&Pl[wv * 16 + ln][32 + quad * 8];

    for (int c4 = 0; c4 < 4; c4++) {
#pragma unroll
      for (int i = 0; i < 2; i++) {
        int e = tid + i * 256;
        int vc = e >> 3, fc = e & 7;
        size_t gidx = (size_t)(c4 * 64 + vc) * 1024 + kt * 64 + fc * 8;
        *(bf8*)&Vh[vc][fc * 8]  = *(const bf8*)&vhg[gidx];
        *(bf8*)&Vl2[vc][fc * 8] = *(const bf8*)&vlg[gidx];
      }
      __syncthreads();  // B3
#pragma unroll
      for (int n2 = 0; n2 < 4; n2++) {
        int nt = c4 * 4 + n2;
        bf8 vh0 = *(const bf8*)&Vh[n2 * 16 + ln][quad * 8];
        bf8 vh1 = *(const bf8*)&Vh[n2 * 16 + ln][32 + quad * 8];
        bf8 vl0 = *(const bf8*)&Vl2[n2 * 16 + ln][quad * 8];
        bf8 vl1 = *(const bf8*)&Vl2[n2 * 16 + ln][32 + quad * 8];
        O[nt] = __builtin_amdgcn_mfma_f32_16x16x32_bf16(ph0, vh0, O[nt], 0, 0, 0);
        O[nt] = __builtin_amdgcn_mfma_f32_16x16x32_bf16(ph1, vh1, O[nt], 0, 0, 0);
        O[nt] = __builtin_amdgcn_mfma_f32_16x16x32_bf16(ph0, vl0, O[nt], 0, 0, 0);
        O[nt] = __builtin_amdgcn_mfma_f32_16x16x32_bf16(ph1, vl1, O[nt], 0, 0, 0);
        O[nt] = __builtin_amdgcn_mfma_f32_16x16x32_bf16(pl0, vh0, O[nt], 0, 0, 0);
        O[nt] = __builtin_amdgcn_mfma_f32_16x16x32_bf16(pl1, vh1, O[nt], 0, 0, 0);
      }
      __syncthreads();  // B4
    }
  }

#pragma unroll
  for (int r = 0; r < 4; r++) {
    float linv = 1.f / l[r];
    int row = qt * 64 + wv * 16 + quad * 4 + r;
    float* dst = ob + (size_t)h * 1048576 + (size_t)(b * 1024 + row) * 256;
#pragma unroll
    for (int nt = 0; nt < 16; nt++)
      dst[nt * 16 + ln] = O[nt][r] * linv;
  }
}

// ---------------------------------------------------------------------------
// BN stats (R4 verbatim)
// ---------------------------------------------------------------------------
__global__ __launch_bounds__(256) void k_bnstats(
    const float* __restrict__ a, const float* __restrict__ b,
    float* __restrict__ stats, int addB)
{
  const int h = blockIdx.y, r0 = blockIdx.x * 64, c = threadIdx.x;
  const float* pa = a + (size_t)h * 1048576 + r0 * 256 + c;
  float s = 0.f, s2 = 0.f;
  if (addB) {
    const float* pb = b + (size_t)h * 1048576 + r0 * 256 + c;
    for (int r = 0; r < 64; r++) {
      float y = pa[r * 256] + pb[r * 256];
      s += y; s2 += y * y;
    }
  } else {
    for (int r = 0; r < 64; r++) {
      float y = pa[r * 256];
      s += y; s2 += y * y;
    }
  }
  atomicAdd(&stats[(h * 256 + c) * 2], s);
  atomicAdd(&stats[(h * 256 + c) * 2 + 1], s2);
}

// ---------------------------------------------------------------------------
// BN apply (R4 verbatim)
// ---------------------------------------------------------------------------
__global__ __launch_bounds__(256) void k_bnapply(
    const float* __restrict__ a, const float* __restrict__ b,
    const float* __restrict__ stats,
    const float* __restrict__ gamma, const float* __restrict__ beta,
    float* __restrict__ dst, int t, int addB, int transposed)
{
  const int h = blockIdx.y, r0 = blockIdx.x * 64, c = threadIdx.x;
  float s  = stats[(h * 256 + c) * 2];
  float s2 = stats[(h * 256 + c) * 2 + 1];
  float mean = s * (1.f / 4096.f);
  float var  = s2 * (1.f / 4096.f) - mean * mean;
  float inv  = rsqrtf(var + EPSV);
  float g  = gamma[(h * TT + t) * 256 + c] * inv;
  float bt = beta[(h * TT + t) * 256 + c];
  const float* pa = a + (size_t)h * 1048576 + r0 * 256 + c;
  const float* pb = addB ? (b + (size_t)h * 1048576 + r0 * 256 + c) : nullptr;
  for (int r = 0; r < 64; r++) {
    float y = pa[r * 256];
    if (addB) y += pb[r * 256];
    float o = (y - mean) * g + bt;
    int rg = r0 + r;
    if (transposed) dst[((size_t)rg * HH + h) * 256 + c] = o;
    else            dst[(size_t)h * 1048576 + rg * 256 + c] = o;
  }
}

// ---------------------------------------------------------------------------
extern "C" void kernel_launch(void* const* d_in, const int* in_sizes, int n_in,
                              void* d_out, int out_size, void* d_ws, size_t ws_size,
                              hipStream_t stream)
{
  const float* x   = (const float*)d_in[0];
  const float* Win = (const float*)d_in[1];
  const float* Wq  = (const float*)d_in[2];
  const float* Wk  = (const float*)d_in[3];
  const float* Wv  = (const float*)d_in[4];
  const float* Wd  = (const float*)d_in[5];
  const float* g1  = (const float*)d_in[6];
  const float* b1  = (const float*)d_in[7];
  const float* g2  = (const float*)d_in[8];
  const float* b2  = (const float*)d_in[9];
  float* out = (float*)d_out;
  float* ws  = (float*)d_ws;

  float* net   = ws;                       // H*BS*V fp32       =  8,388,608 f
  float* tmp   = net + 8388608;            // H*BS*V fp32       =  8,388,608 f
  float* stats = tmp + 8388608;            // 8 phases * H*V*2  =     32,768 f
  // q/k split-f16 hi/lo, [h*4+b][s][kd] halves (reuses old qtg/ktg region)
  _Float16* qph = (_Float16*)(stats + 32768);  // 2,097,152 h
  _Float16* qpl = qph + 2097152;               // 2,097,152 h
  _Float16* kph = qpl + 2097152;               // 2,097,152 h
  _Float16* kpl = kph + 2097152;               // 2,097,152 h
  short* vth   = (short*)(kpl + 2097152);  // H*B*V*S bf16 hi   =  8,388,608 s
  short* vtl   = vth + 8388608;            // H*B*V*S bf16 lo   =  8,388,608 s
  _Float16* wph = (_Float16*)(vtl + 8388608);  // prepped weights hi = 1,310,720 h
  _Float16* wpl = wph + 1310720;               // prepped weights lo = 1,310,720 h

  hipMemsetAsync(stats, 0, 8 * HH * VV * 2 * sizeof(float), stream);

  k_in_dense<<<dim3(64, 4), 256, 0, stream>>>(x, Win, net);

  for (int t = 0; t < TT; t++) {
    float* st1 = stats + (t * 2 + 0) * HH * VV * 2;
    float* st2 = stats + (t * 2 + 1) * HH * VV * 2;

    k_prep<<<dim3(10, 4, 8), 256, 0, stream>>>(Wq, Wk, Wv, Wd, wph, wpl, t);
    k_mm_qkv<<<dim3(64, 6, 8), 256, 0, stream>>>(net, wph, wpl, qph, qpl, kph, kpl, vth, vtl);
    k_attn<<<dim3(16, 4, 8), 256, 0, stream>>>(qph, qpl, kph, kpl, vth, vtl, tmp);

    k_bnstats<<<dim3(64, 8), 256, 0, stream>>>(net, tmp, st1, 1);
    k_bnapply<<<dim3(64, 8), 256, 0, stream>>>(net, tmp, st1, g1, b1, net, t, 1, 0);

    k_mm_dense<<<dim3(64, 4, 8), 256, 0, stream>>>(net, wph, wpl, tmp);

    k_bnstats<<<dim3(64, 8), 256, 0, stream>>>(tmp, nullptr, st2, 0);
    if (t < TT - 1)
      k_bnapply<<<dim3(64, 8), 256, 0, stream>>>(tmp, nullptr, st2, g2, b2, net, t, 0, 0);
    else
      k_bnapply<<<dim3(64, 8), 256, 0, stream>>>(tmp, nullptr, st2, g2, b2, out, t, 0, 1);
  }
}